// Round 1
// baseline (599.172 us; speedup 1.0000x reference)
//
#include <hip/hip_runtime.h>
#include <math.h>

#define NHID 128
#define NFEAT 256
#define NCLASS 40

// ---------------------------------------------------------------------------
// CSR build: histogram -> 3-phase exclusive scan -> fill
// ---------------------------------------------------------------------------
__global__ __launch_bounds__(256) void hist_kernel(const int* __restrict__ edst,
                                                   int* __restrict__ counts, int E) {
    int e = blockIdx.x * 256 + threadIdx.x;
    if (e < E) atomicAdd(&counts[edst[e]], 1);
}

__global__ __launch_bounds__(256) void scan_s1(const int* __restrict__ counts,
                                               int* __restrict__ partials, int N) {
    __shared__ int lds[256];
    int tid = threadIdx.x;
    int base = blockIdx.x * 1024 + tid * 4;
    int s = 0;
#pragma unroll
    for (int j = 0; j < 4; ++j)
        if (base + j < N) s += counts[base + j];
    lds[tid] = s;
    __syncthreads();
    for (int off = 128; off > 0; off >>= 1) {
        if (tid < off) lds[tid] += lds[tid + off];
        __syncthreads();
    }
    if (tid == 0) partials[blockIdx.x] = lds[0];
}

__global__ void scan_s2(int* partials, int* row_ptr, int NB, int N) {
    if (threadIdx.x == 0 && blockIdx.x == 0) {
        int run = 0;
        for (int i = 0; i < NB; ++i) { int t = partials[i]; partials[i] = run; run += t; }
        row_ptr[N] = run;
    }
}

__global__ __launch_bounds__(256) void scan_s3(const int* __restrict__ counts,
                                               const int* __restrict__ partials,
                                               int* __restrict__ row_ptr, int N) {
    __shared__ int lds[256];
    int tid = threadIdx.x;
    int base = blockIdx.x * 1024 + tid * 4;
    int v[4];
    int s = 0;
#pragma unroll
    for (int j = 0; j < 4; ++j) { v[j] = (base + j < N) ? counts[base + j] : 0; s += v[j]; }
    lds[tid] = s;
    __syncthreads();
    for (int off = 1; off < 256; off <<= 1) {
        int t = (tid >= off) ? lds[tid - off] : 0;
        __syncthreads();
        lds[tid] += t;
        __syncthreads();
    }
    int excl = lds[tid] - s + partials[blockIdx.x];
#pragma unroll
    for (int j = 0; j < 4; ++j) {
        if (base + j < N) row_ptr[base + j] = excl;
        excl += v[j];
    }
}

__global__ __launch_bounds__(256) void fill_csr(const int* __restrict__ esrc,
                                                const int* __restrict__ edst,
                                                const int* __restrict__ row_ptr,
                                                int* __restrict__ cursor,
                                                int* __restrict__ srcs, int E) {
    int e = blockIdx.x * 256 + threadIdx.x;
    if (e < E) {
        int d = edst[e];
        int p = atomicAdd(&cursor[d], 1);
        srcs[row_ptr[d] + p] = esrc[e];
    }
}

// ---------------------------------------------------------------------------
// Aggregation: one wave per destination node, lane covers 2 features (float2).
// Each neighbor read = 64 lanes x 8B = 512B coalesced.
// ---------------------------------------------------------------------------
__global__ __launch_bounds__(256) void aggregate(const float* __restrict__ h,
                                                 const int* __restrict__ row_ptr,
                                                 const int* __restrict__ srcs,
                                                 float* __restrict__ agg, int N) {
    int node = blockIdx.x * 4 + (threadIdx.x >> 6);
    int lane = threadIdx.x & 63;
    if (node >= N) return;
    int beg = row_ptr[node];
    int end = row_ptr[node + 1];
    const float2* h2 = (const float2*)h;
    float2 acc = make_float2(0.f, 0.f);
    for (int e = beg; e < end; ++e) {
        int s = srcs[e];
        float2 vv = h2[(size_t)s * 64 + lane];
        acc.x += vv.x;
        acc.y += vv.y;
    }
    ((float2*)agg)[(size_t)node * 64 + lane] = acc;
}

// ---------------------------------------------------------------------------
// fp32 GEMM, N fixed = 128, fused (A + A2) add + bias + ReLU.
// Tile: 32 rows x 128 cols, BK = 64. LDS = 8KB(sA) + 32KB(sW) = 40KB -> 4 blk/CU.
// Thread: 4 rows x 4 cols. sA reads: 2 distinct addr/wave (broadcast, free).
// sW reads: stride-1 float4 across 32 lanes (conflict-free).
// ---------------------------------------------------------------------------
__global__ __launch_bounds__(256) void gemm_n128_bias_relu(
    const float* __restrict__ A, const float* __restrict__ A2,
    const float* __restrict__ W, const float* __restrict__ bias,
    float* __restrict__ out, int M, int K) {
    __shared__ float sA[32 * 64];
    __shared__ float sW[64 * 128];
    int tid = threadIdx.x;
    int row0 = blockIdx.x * 32;
    int rg = tid >> 5;  // 0..7 -> rows rg*4 .. rg*4+3
    int cg = tid & 31;  // 0..31 -> cols cg*4 .. cg*4+3

    float4 acc0 = make_float4(0.f, 0.f, 0.f, 0.f);
    float4 acc1 = acc0, acc2 = acc0, acc3 = acc0;

    for (int k0 = 0; k0 < K; k0 += 64) {
        // stage W chunk (64 x 128), contiguous
#pragma unroll
        for (int it = 0; it < 8; ++it) {
            int i = tid * 4 + it * 1024;
            *(float4*)&sW[i] = *(const float4*)&W[(size_t)k0 * 128 + i];
        }
        // stage A chunk (32 x 64), optionally fused + A2
#pragma unroll
        for (int it = 0; it < 2; ++it) {
            int i = tid * 4 + it * 1024;
            int r = i >> 6, k = i & 63;
            int rr = min(row0 + r, M - 1);
            float4 v = *(const float4*)&A[(size_t)rr * K + k0 + k];
            if (A2) {
                float4 u = *(const float4*)&A2[(size_t)rr * K + k0 + k];
                v.x += u.x; v.y += u.y; v.z += u.z; v.w += u.w;
            }
            *(float4*)&sA[i] = v;
        }
        __syncthreads();

        for (int k = 0; k < 64; k += 4) {
            float4 a0 = *(const float4*)&sA[(rg * 4 + 0) * 64 + k];
            float4 a1 = *(const float4*)&sA[(rg * 4 + 1) * 64 + k];
            float4 a2 = *(const float4*)&sA[(rg * 4 + 2) * 64 + k];
            float4 a3 = *(const float4*)&sA[(rg * 4 + 3) * 64 + k];
#pragma unroll
            for (int kk = 0; kk < 4; ++kk) {
                float4 w = *(const float4*)&sW[(k + kk) * 128 + cg * 4];
                float x0 = ((const float*)&a0)[kk];
                float x1 = ((const float*)&a1)[kk];
                float x2 = ((const float*)&a2)[kk];
                float x3 = ((const float*)&a3)[kk];
                acc0.x += x0 * w.x; acc0.y += x0 * w.y; acc0.z += x0 * w.z; acc0.w += x0 * w.w;
                acc1.x += x1 * w.x; acc1.y += x1 * w.y; acc1.z += x1 * w.z; acc1.w += x1 * w.w;
                acc2.x += x2 * w.x; acc2.y += x2 * w.y; acc2.z += x2 * w.z; acc2.w += x2 * w.w;
                acc3.x += x3 * w.x; acc3.y += x3 * w.y; acc3.z += x3 * w.z; acc3.w += x3 * w.w;
            }
        }
        __syncthreads();
    }

    float4 bv = *(const float4*)&bias[cg * 4];
    float4 accs[4] = {acc0, acc1, acc2, acc3};
#pragma unroll
    for (int r = 0; r < 4; ++r) {
        int row = row0 + rg * 4 + r;
        if (row < M) {
            float4 o;
            o.x = fmaxf(accs[r].x + bv.x, 0.f);
            o.y = fmaxf(accs[r].y + bv.y, 0.f);
            o.z = fmaxf(accs[r].z + bv.z, 0.f);
            o.w = fmaxf(accs[r].w + bv.w, 0.f);
            *(float4*)&out[(size_t)row * 128 + cg * 4] = o;
        }
    }
}

// ---------------------------------------------------------------------------
// Output: logits = h @ W_out + b_out (K=128, C=40), then row log_softmax.
// Block = 256 threads, 32 rows/block; 8 lanes per row x 5 classes each.
// sH padded to stride 132 -> row reads hit distinct banks (4r+k mod 32).
// ---------------------------------------------------------------------------
__global__ __launch_bounds__(256) void out_logsoftmax(const float* __restrict__ h,
                                                      const float* __restrict__ Wout,
                                                      const float* __restrict__ bout,
                                                      float* __restrict__ out, int M) {
    __shared__ float sW[128 * NCLASS];  // 20 KB
    __shared__ float sb[NCLASS];
    __shared__ float sH[32 * 132];      // ~16.9 KB, padded stride
    int tid = threadIdx.x;
    for (int i = tid; i < 128 * NCLASS; i += 256) sW[i] = Wout[i];
    if (tid < NCLASS) sb[tid] = bout[tid];
    int row0 = blockIdx.x * 32;
#pragma unroll
    for (int it = 0; it < 4; ++it) {
        int i = tid * 4 + it * 1024;
        int r = i >> 7, k = i & 127;
        int rr = min(row0 + r, M - 1);
        *(float4*)&sH[r * 132 + k] = *(const float4*)&h[(size_t)rr * 128 + k];
    }
    __syncthreads();

    int r = tid >> 3;   // 0..31
    int cg = tid & 7;   // 8 groups of 5 classes
    float z[5];
#pragma unroll
    for (int j = 0; j < 5; ++j) z[j] = sb[cg * 5 + j];
    for (int k = 0; k < 128; ++k) {
        float a = sH[r * 132 + k];
#pragma unroll
        for (int j = 0; j < 5; ++j) z[j] += a * sW[k * NCLASS + cg * 5 + j];
    }
    float m = z[0];
#pragma unroll
    for (int j = 1; j < 5; ++j) m = fmaxf(m, z[j]);
    for (int off = 1; off < 8; off <<= 1) m = fmaxf(m, __shfl_xor(m, off));
    float s = 0.f;
#pragma unroll
    for (int j = 0; j < 5; ++j) s += expf(z[j] - m);
    for (int off = 1; off < 8; off <<= 1) s += __shfl_xor(s, off);
    float lse = m + logf(s);
    int row = row0 + r;
    if (row < M) {
#pragma unroll
        for (int j = 0; j < 5; ++j) out[(size_t)row * NCLASS + cg * 5 + j] = z[j] - lse;
    }
}

// ---------------------------------------------------------------------------
extern "C" void kernel_launch(void* const* d_in, const int* in_sizes, int n_in,
                              void* d_out, int out_size, void* d_ws, size_t ws_size,
                              hipStream_t stream) {
    const float* x      = (const float*)d_in[0];
    const int*   esrc   = (const int*)d_in[1];
    const int*   edst   = (const int*)d_in[2];
    const float* W_in   = (const float*)d_in[3];
    const float* b_in   = (const float*)d_in[4];
    const float* W_mlps = (const float*)d_in[5];
    const float* b_mlps = (const float*)d_in[6];
    const float* W_out  = (const float*)d_in[7];
    const float* b_out  = (const float*)d_in[8];
    float* out = (float*)d_out;

    int N = in_sizes[0] / NFEAT;  // 50000
    int E = in_sizes[1];          // 800000

    // workspace carve (~80.4 MB)
    char* ws = (char*)d_ws;
    size_t hb = (((size_t)N * NHID * sizeof(float)) + 255) & ~(size_t)255;
    float* h_a = (float*)ws;
    float* h_b = (float*)(ws + hb);
    float* agg = (float*)(ws + 2 * hb);
    char* ip = ws + 3 * hb;
    int* row_ptr = (int*)ip;  ip += (((size_t)(N + 1) * 4) + 255) & ~(size_t)255;
    int* counts  = (int*)ip;  ip += (((size_t)N * 4) + 255) & ~(size_t)255;
    int* srcs    = (int*)ip;  ip += (((size_t)E * 4) + 255) & ~(size_t)255;
    int* partials = (int*)ip;

    int NB = (N + 1023) / 1024;
    int eb = (E + 255) / 256;

    // ---- CSR build ----
    hipMemsetAsync(counts, 0, (size_t)N * 4, stream);
    hist_kernel<<<eb, 256, 0, stream>>>(edst, counts, E);
    scan_s1<<<NB, 256, 0, stream>>>(counts, partials, N);
    scan_s2<<<1, 1, 0, stream>>>(partials, row_ptr, NB, N);
    scan_s3<<<NB, 256, 0, stream>>>(counts, partials, row_ptr, N);
    hipMemsetAsync(counts, 0, (size_t)N * 4, stream);  // reuse as fill cursor
    fill_csr<<<eb, 256, 0, stream>>>(esrc, edst, row_ptr, counts, srcs, E);

    int gemm_blocks = (N + 31) / 32;
    // ---- input layer: h = relu(x @ W_in + b_in) ----
    gemm_n128_bias_relu<<<gemm_blocks, 256, 0, stream>>>(x, nullptr, W_in, b_in, h_a, N, NFEAT);

    // ---- 3 GIN layers ----
    float* cur = h_a;
    float* nxt = h_b;
    for (int i = 0; i < 3; ++i) {
        aggregate<<<(N + 3) / 4, 256, 0, stream>>>(cur, row_ptr, srcs, agg, N);
        gemm_n128_bias_relu<<<gemm_blocks, 256, 0, stream>>>(
            cur, agg, W_mlps + (size_t)i * NHID * NHID, b_mlps + (size_t)i * NHID, nxt, N, NHID);
        float* t = cur; cur = nxt; nxt = t;
    }

    // ---- output layer + log_softmax ----
    out_logsoftmax<<<gemm_blocks, 256, 0, stream>>>(cur, W_out, b_out, out, N);
}

// Round 2
// 413.527 us; speedup vs baseline: 1.4489x; 1.4489x over previous
//
#include <hip/hip_runtime.h>
#include <math.h>

#define NHID 128
#define NFEAT 256
#define NCLASS 40

typedef __bf16 bf16x8 __attribute__((ext_vector_type(8)));
typedef __bf16 bf16x4 __attribute__((ext_vector_type(4)));
typedef float floatx4 __attribute__((ext_vector_type(4)));

// ---------------------------------------------------------------------------
// CSR build: histogram -> 3-phase exclusive scan -> fill  (unchanged, works)
// ---------------------------------------------------------------------------
__global__ __launch_bounds__(256) void hist_kernel(const int* __restrict__ edst,
                                                   int* __restrict__ counts, int E) {
    int e = blockIdx.x * 256 + threadIdx.x;
    if (e < E) atomicAdd(&counts[edst[e]], 1);
}

__global__ __launch_bounds__(256) void scan_s1(const int* __restrict__ counts,
                                               int* __restrict__ partials, int N) {
    __shared__ int lds[256];
    int tid = threadIdx.x;
    int base = blockIdx.x * 1024 + tid * 4;
    int s = 0;
#pragma unroll
    for (int j = 0; j < 4; ++j)
        if (base + j < N) s += counts[base + j];
    lds[tid] = s;
    __syncthreads();
    for (int off = 128; off > 0; off >>= 1) {
        if (tid < off) lds[tid] += lds[tid + off];
        __syncthreads();
    }
    if (tid == 0) partials[blockIdx.x] = lds[0];
}

__global__ void scan_s2(int* partials, int* row_ptr, int NB, int N) {
    if (threadIdx.x == 0 && blockIdx.x == 0) {
        int run = 0;
        for (int i = 0; i < NB; ++i) { int t = partials[i]; partials[i] = run; run += t; }
        row_ptr[N] = run;
    }
}

__global__ __launch_bounds__(256) void scan_s3(const int* __restrict__ counts,
                                               const int* __restrict__ partials,
                                               int* __restrict__ row_ptr, int N) {
    __shared__ int lds[256];
    int tid = threadIdx.x;
    int base = blockIdx.x * 1024 + tid * 4;
    int v[4];
    int s = 0;
#pragma unroll
    for (int j = 0; j < 4; ++j) { v[j] = (base + j < N) ? counts[base + j] : 0; s += v[j]; }
    lds[tid] = s;
    __syncthreads();
    for (int off = 1; off < 256; off <<= 1) {
        int t = (tid >= off) ? lds[tid - off] : 0;
        __syncthreads();
        lds[tid] += t;
        __syncthreads();
    }
    int excl = lds[tid] - s + partials[blockIdx.x];
#pragma unroll
    for (int j = 0; j < 4; ++j) {
        if (base + j < N) row_ptr[base + j] = excl;
        excl += v[j];
    }
}

__global__ __launch_bounds__(256) void fill_csr(const int* __restrict__ esrc,
                                                const int* __restrict__ edst,
                                                const int* __restrict__ row_ptr,
                                                int* __restrict__ cursor,
                                                int* __restrict__ srcs, int E) {
    int e = blockIdx.x * 256 + threadIdx.x;
    if (e < E) {
        int d = edst[e];
        int p = atomicAdd(&cursor[d], 1);
        srcs[row_ptr[d] + p] = esrc[e];
    }
}

// ---------------------------------------------------------------------------
// Weight prep: transpose + split fp32 W[K][128] -> Wt_hi/lo[128][K] bf16.
// L matrices batched. dst index = ((l*128 + n)*K + k).
// ---------------------------------------------------------------------------
template <int K>
__global__ __launch_bounds__(256) void transpose_split(const float* __restrict__ src,
                                                       __bf16* __restrict__ dhi,
                                                       __bf16* __restrict__ dlo, int total) {
    int i = blockIdx.x * 256 + threadIdx.x;
    if (i >= total) return;
    int per = 128 * K;
    int l = i / per;
    int r = i - l * per;
    int n = r / K;
    int k = r - n * K;
    float v = src[(size_t)l * per + (size_t)k * 128 + n];
    __bf16 hi = (__bf16)v;
    dhi[i] = hi;
    dlo[i] = (__bf16)(v - (float)hi);
}

// ---------------------------------------------------------------------------
// Aggregation over bf16 h_hi. One wave per node. 2 edges per instruction
// (32 lanes x 8B each = 256B row), unrolled x2 -> 4 gathers in flight.
// Accumulate fp32, write fp32 agg.
// ---------------------------------------------------------------------------
__global__ __launch_bounds__(256) void aggregate_bf16(const __bf16* __restrict__ h,
                                                      const int* __restrict__ row_ptr,
                                                      const int* __restrict__ srcs,
                                                      float* __restrict__ agg, int N) {
    int tid = threadIdx.x;
    int node = blockIdx.x * 4 + (tid >> 6);
    if (node >= N) return;
    int lane = tid & 63;
    int p = lane >> 5;   // edge parity
    int c = lane & 31;   // feature quad: features c*4..c*4+3
    int beg = row_ptr[node];
    int end = row_ptr[node + 1];
    const uint2* h2 = (const uint2*)h;  // row = 32 uint2
    float a0 = 0.f, a1 = 0.f, a2 = 0.f, a3 = 0.f;
    float b0 = 0.f, b1 = 0.f, b2 = 0.f, b3 = 0.f;
    int e = beg + p;
    for (; e + 2 < end; e += 4) {
        int s0 = srcs[e];
        int s1 = srcs[e + 2];
        uint2 u0 = h2[(size_t)s0 * 32 + c];
        uint2 u1 = h2[(size_t)s1 * 32 + c];
        a0 += __uint_as_float(u0.x << 16);
        a1 += __uint_as_float(u0.x & 0xffff0000u);
        a2 += __uint_as_float(u0.y << 16);
        a3 += __uint_as_float(u0.y & 0xffff0000u);
        b0 += __uint_as_float(u1.x << 16);
        b1 += __uint_as_float(u1.x & 0xffff0000u);
        b2 += __uint_as_float(u1.y << 16);
        b3 += __uint_as_float(u1.y & 0xffff0000u);
    }
    if (e < end) {
        int s0 = srcs[e];
        uint2 u0 = h2[(size_t)s0 * 32 + c];
        a0 += __uint_as_float(u0.x << 16);
        a1 += __uint_as_float(u0.x & 0xffff0000u);
        a2 += __uint_as_float(u0.y << 16);
        a3 += __uint_as_float(u0.y & 0xffff0000u);
    }
    a0 += b0; a1 += b1; a2 += b2; a3 += b3;
    a0 += __shfl_xor(a0, 32);
    a1 += __shfl_xor(a1, 32);
    a2 += __shfl_xor(a2, 32);
    a3 += __shfl_xor(a3, 32);
    if (p == 0) {
        float4 v = make_float4(a0, a1, a2, a3);
        *(float4*)&agg[(size_t)node * 128 + c * 4] = v;
    }
}

// ---------------------------------------------------------------------------
// MFMA GEMM: out = relu(A @ W + b), N=128 fixed, split-precision bf16.
// MODE 0: A = fp32 Af[M][K]           (input layer, K=256)
// MODE 1: A = cvt(Ahi)+cvt(Alo)+A2    (GIN layers, K=128, A2 = fp32 agg)
// Block: 256 thr (4 waves), tile 64 rows x 128 cols, BK=64.
// LDS 48KB (XOR-swizzled, conflict-free ds_read_b128) -> 3 blocks/CU.
// Per K-step-32: 3 MFMAs/tile (hi*hi + lo*hi + hi*lo) ~ fp32 accuracy.
// Epilogue: bias+relu in regs -> fp32 LDS transpose -> coalesced bf16 hi/lo.
// ---------------------------------------------------------------------------
template <int MODE>
__global__ __launch_bounds__(256) void gemm_mfma(
    const float* __restrict__ Af, const __bf16* __restrict__ Ahi,
    const __bf16* __restrict__ Alo, const float* __restrict__ A2,
    const __bf16* __restrict__ Wthi, const __bf16* __restrict__ Wtlo,
    const float* __restrict__ bias, __bf16* __restrict__ Ohi,
    __bf16* __restrict__ Olo, int M, int K) {
    __shared__ __align__(16) char smem[49152];
    __bf16* sAhi = (__bf16*)smem;                // 64x64 bf16 = 8KB
    __bf16* sAlo = (__bf16*)(smem + 8192);       // 8KB
    __bf16* sWhi = (__bf16*)(smem + 16384);      // 128x64 bf16 = 16KB
    __bf16* sWlo = (__bf16*)(smem + 32768);      // 16KB

    int tid = threadIdx.x;
    int row0 = blockIdx.x * 64;
    int wave = tid >> 6;
    int l = tid & 63;
    int m16 = l & 15;
    int q = l >> 4;
    int axor = m16 & 7;
    int arow = wave * 16 + m16;

    floatx4 acc[8];
#pragma unroll
    for (int t = 0; t < 8; ++t) acc[t] = (floatx4){0.f, 0.f, 0.f, 0.f};

    for (int k0 = 0; k0 < K; k0 += 64) {
        // ---- stage A tile (64 x 64) ----
#pragma unroll
        for (int it = 0; it < 2; ++it) {
            int lin = it * 2048 + tid * 8;
            int row = lin >> 6, k = lin & 63;
            int g = min(row0 + row, M - 1);
            float s[8];
            if (MODE == 0) {
                float4 v0 = *(const float4*)&Af[(size_t)g * K + k0 + k];
                float4 v1 = *(const float4*)&Af[(size_t)g * K + k0 + k + 4];
                s[0] = v0.x; s[1] = v0.y; s[2] = v0.z; s[3] = v0.w;
                s[4] = v1.x; s[5] = v1.y; s[6] = v1.z; s[7] = v1.w;
            } else {
                bf16x8 hv = *(const bf16x8*)&Ahi[(size_t)g * 128 + k0 + k];
                bf16x8 lv = *(const bf16x8*)&Alo[(size_t)g * 128 + k0 + k];
                float4 g0 = *(const float4*)&A2[(size_t)g * 128 + k0 + k];
                float4 g1 = *(const float4*)&A2[(size_t)g * 128 + k0 + k + 4];
                s[0] = (float)hv[0] + (float)lv[0] + g0.x;
                s[1] = (float)hv[1] + (float)lv[1] + g0.y;
                s[2] = (float)hv[2] + (float)lv[2] + g0.z;
                s[3] = (float)hv[3] + (float)lv[3] + g0.w;
                s[4] = (float)hv[4] + (float)lv[4] + g1.x;
                s[5] = (float)hv[5] + (float)lv[5] + g1.y;
                s[6] = (float)hv[6] + (float)lv[6] + g1.z;
                s[7] = (float)hv[7] + (float)lv[7] + g1.w;
            }
            bf16x8 shi, slo;
#pragma unroll
            for (int j = 0; j < 8; ++j) {
                __bf16 h = (__bf16)s[j];
                shi[j] = h;
                slo[j] = (__bf16)(s[j] - (float)h);
            }
            int off = row * 64 + (((k >> 3) ^ (row & 7)) << 3);
            *(bf16x8*)(sAhi + off) = shi;
            *(bf16x8*)(sAlo + off) = slo;
        }
        // ---- stage W tile (128 x 64), already transposed+split in global ----
#pragma unroll
        for (int it = 0; it < 4; ++it) {
            int lin = it * 2048 + tid * 8;
            int n = lin >> 6, kk = lin & 63;
            bf16x8 wh = *(const bf16x8*)&Wthi[(size_t)n * K + k0 + kk];
            bf16x8 wl = *(const bf16x8*)&Wtlo[(size_t)n * K + k0 + kk];
            int off = n * 64 + (((kk >> 3) ^ (n & 7)) << 3);
            *(bf16x8*)(sWhi + off) = wh;
            *(bf16x8*)(sWlo + off) = wl;
        }
        __syncthreads();

#pragma unroll
        for (int s = 0; s < 2; ++s) {
            int sw = (((s * 4 + q) ^ axor) << 3);
            bf16x8 ahi = *(bf16x8*)(sAhi + arow * 64 + sw);
            bf16x8 alo = *(bf16x8*)(sAlo + arow * 64 + sw);
#pragma unroll
            for (int t = 0; t < 8; ++t) {
                int n = t * 16 + m16;
                bf16x8 bhi = *(bf16x8*)(sWhi + n * 64 + sw);
                bf16x8 blo = *(bf16x8*)(sWlo + n * 64 + sw);
                acc[t] = __builtin_amdgcn_mfma_f32_16x16x32_bf16(ahi, bhi, acc[t], 0, 0, 0);
                acc[t] = __builtin_amdgcn_mfma_f32_16x16x32_bf16(alo, bhi, acc[t], 0, 0, 0);
                acc[t] = __builtin_amdgcn_mfma_f32_16x16x32_bf16(ahi, blo, acc[t], 0, 0, 0);
            }
        }
        __syncthreads();
    }

    // ---- epilogue: bias + relu -> fp32 LDS (reuse sW region) -> hi/lo bf16 ----
    float* eps = (float*)(smem + 16384);  // 64*128*4 = 32KB
#pragma unroll
    for (int t = 0; t < 8; ++t) {
        int col = t * 16 + m16;
        float bb = bias[col];
#pragma unroll
        for (int i = 0; i < 4; ++i) {
            int row = wave * 16 + q * 4 + i;
            eps[row * 128 + col] = fmaxf(acc[t][i] + bb, 0.f);
        }
    }
    __syncthreads();
#pragma unroll
    for (int it = 0; it < 8; ++it) {
        int lin = it * 1024 + tid * 4;
        int row = lin >> 7, col = lin & 127;
        int g = row0 + row;
        if (g < M) {
            float4 v = *(float4*)(eps + lin);
            bf16x4 hi, lo;
            float vv[4] = {v.x, v.y, v.z, v.w};
#pragma unroll
            for (int j = 0; j < 4; ++j) {
                __bf16 h = (__bf16)vv[j];
                hi[j] = h;
                lo[j] = (__bf16)(vv[j] - (float)h);
            }
            *(bf16x4*)&Ohi[(size_t)g * 128 + col] = hi;
            *(bf16x4*)&Olo[(size_t)g * 128 + col] = lo;
        }
    }
}

// ---------------------------------------------------------------------------
// Output: logits = h @ W_out + b_out (K=128, C=40), then row log_softmax.
// h reconstructed fp32 from hi+lo. Compute fp32 (vector ALU, tiny GEMM).
// ---------------------------------------------------------------------------
__global__ __launch_bounds__(256) void out_logsoftmax(const __bf16* __restrict__ hhi,
                                                      const __bf16* __restrict__ hlo,
                                                      const float* __restrict__ Wout,
                                                      const float* __restrict__ bout,
                                                      float* __restrict__ out, int M) {
    __shared__ float sW[128 * NCLASS];  // 20 KB
    __shared__ float sb[NCLASS];
    __shared__ float sH[32 * 132];      // padded stride
    int tid = threadIdx.x;
    for (int i = tid; i < 128 * NCLASS; i += 256) sW[i] = Wout[i];
    if (tid < NCLASS) sb[tid] = bout[tid];
    int row0 = blockIdx.x * 32;
#pragma unroll
    for (int it = 0; it < 4; ++it) {
        int i = tid * 4 + it * 1024;
        int r = i >> 7, k = i & 127;
        int rr = min(row0 + r, M - 1);
        uint2 uh = *(const uint2*)&hhi[(size_t)rr * 128 + k];
        uint2 ul = *(const uint2*)&hlo[(size_t)rr * 128 + k];
        sH[r * 132 + k + 0] = __uint_as_float(uh.x << 16) + __uint_as_float(ul.x << 16);
        sH[r * 132 + k + 1] = __uint_as_float(uh.x & 0xffff0000u) + __uint_as_float(ul.x & 0xffff0000u);
        sH[r * 132 + k + 2] = __uint_as_float(uh.y << 16) + __uint_as_float(ul.y << 16);
        sH[r * 132 + k + 3] = __uint_as_float(uh.y & 0xffff0000u) + __uint_as_float(ul.y & 0xffff0000u);
    }
    __syncthreads();

    int r = tid >> 3;
    int cg = tid & 7;
    float z[5];
#pragma unroll
    for (int j = 0; j < 5; ++j) z[j] = sb[cg * 5 + j];
    for (int k = 0; k < 128; ++k) {
        float a = sH[r * 132 + k];
#pragma unroll
        for (int j = 0; j < 5; ++j) z[j] += a * sW[k * NCLASS + cg * 5 + j];
    }
    float m = z[0];
#pragma unroll
    for (int j = 1; j < 5; ++j) m = fmaxf(m, z[j]);
    for (int off = 1; off < 8; off <<= 1) m = fmaxf(m, __shfl_xor(m, off));
    float s = 0.f;
#pragma unroll
    for (int j = 0; j < 5; ++j) s += expf(z[j] - m);
    for (int off = 1; off < 8; off <<= 1) s += __shfl_xor(s, off);
    float lse = m + logf(s);
    int row = row0 + r;
    if (row < M) {
#pragma unroll
        for (int j = 0; j < 5; ++j) out[(size_t)row * NCLASS + cg * 5 + j] = z[j] - lse;
    }
}

// ---------------------------------------------------------------------------
extern "C" void kernel_launch(void* const* d_in, const int* in_sizes, int n_in,
                              void* d_out, int out_size, void* d_ws, size_t ws_size,
                              hipStream_t stream) {
    const float* x      = (const float*)d_in[0];
    const int*   esrc   = (const int*)d_in[1];
    const int*   edst   = (const int*)d_in[2];
    const float* W_in   = (const float*)d_in[3];
    const float* b_in   = (const float*)d_in[4];
    const float* W_mlps = (const float*)d_in[5];
    const float* b_mlps = (const float*)d_in[6];
    const float* W_out  = (const float*)d_in[7];
    const float* b_out  = (const float*)d_in[8];
    float* out = (float*)d_out;

    int N = in_sizes[0] / NFEAT;  // 50000
    int E = in_sizes[1];          // 800000

    // workspace carve (~81 MB)
    char* ws = (char*)d_ws;
    size_t hb = (((size_t)N * NHID * sizeof(__bf16)) + 255) & ~(size_t)255;  // 12.8MB
    __bf16* h_hi_a = (__bf16*)ws;
    __bf16* h_lo_a = (__bf16*)(ws + hb);
    __bf16* h_hi_b = (__bf16*)(ws + 2 * hb);
    __bf16* h_lo_b = (__bf16*)(ws + 3 * hb);
    float*  agg    = (float*)(ws + 4 * hb);                       // 25.6MB
    char* ip = ws + 4 * hb + 2 * hb;  // agg = 2*hb bytes
    int* row_ptr  = (int*)ip;  ip += (((size_t)(N + 1) * 4) + 255) & ~(size_t)255;
    int* counts   = (int*)ip;  ip += (((size_t)N * 4) + 255) & ~(size_t)255;
    int* srcs     = (int*)ip;  ip += (((size_t)E * 4) + 255) & ~(size_t)255;
    int* partials = (int*)ip;  ip += 4096;
    __bf16* Wt_in_hi   = (__bf16*)ip;  ip += 128 * NFEAT * 2;
    __bf16* Wt_in_lo   = (__bf16*)ip;  ip += 128 * NFEAT * 2;
    __bf16* Wt_mlps_hi = (__bf16*)ip;  ip += 3 * 128 * NHID * 2;
    __bf16* Wt_mlps_lo = (__bf16*)ip;  ip += 3 * 128 * NHID * 2;

    int NB = (N + 1023) / 1024;
    int eb = (E + 255) / 256;

    // ---- CSR build ----
    hipMemsetAsync(counts, 0, (size_t)N * 4, stream);
    hist_kernel<<<eb, 256, 0, stream>>>(edst, counts, E);
    scan_s1<<<NB, 256, 0, stream>>>(counts, partials, N);
    scan_s2<<<1, 1, 0, stream>>>(partials, row_ptr, NB, N);
    scan_s3<<<NB, 256, 0, stream>>>(counts, partials, row_ptr, N);
    hipMemsetAsync(counts, 0, (size_t)N * 4, stream);
    fill_csr<<<eb, 256, 0, stream>>>(esrc, edst, row_ptr, counts, srcs, E);

    // ---- weight prep (transpose + hi/lo split) ----
    transpose_split<NFEAT><<<(128 * NFEAT + 255) / 256, 256, 0, stream>>>(
        W_in, Wt_in_hi, Wt_in_lo, 128 * NFEAT);
    transpose_split<NHID><<<(3 * 128 * NHID + 255) / 256, 256, 0, stream>>>(
        W_mlps, Wt_mlps_hi, Wt_mlps_lo, 3 * 128 * NHID);

    int gb = (N + 63) / 64;
    // ---- input layer ----
    gemm_mfma<0><<<gb, 256, 0, stream>>>(x, (const __bf16*)nullptr, (const __bf16*)nullptr,
                                         (const float*)nullptr, Wt_in_hi, Wt_in_lo, b_in,
                                         h_hi_a, h_lo_a, N, NFEAT);

    // ---- 3 GIN layers ----
    __bf16* cur_hi = h_hi_a; __bf16* cur_lo = h_lo_a;
    __bf16* nxt_hi = h_hi_b; __bf16* nxt_lo = h_lo_b;
    for (int i = 0; i < 3; ++i) {
        aggregate_bf16<<<(N + 3) / 4, 256, 0, stream>>>(cur_hi, row_ptr, srcs, agg, N);
        gemm_mfma<1><<<gb, 256, 0, stream>>>(
            (const float*)nullptr, cur_hi, cur_lo, agg,
            Wt_mlps_hi + (size_t)i * 128 * NHID, Wt_mlps_lo + (size_t)i * 128 * NHID,
            b_mlps + (size_t)i * NHID, nxt_hi, nxt_lo, N, NHID);
        __bf16* t;
        t = cur_hi; cur_hi = nxt_hi; nxt_hi = t;
        t = cur_lo; cur_lo = nxt_lo; nxt_lo = t;
    }

    // ---- output layer + log_softmax ----
    out_logsoftmax<<<(N + 31) / 32, 256, 0, stream>>>(cur_hi, cur_lo, W_out, b_out, out, N);
}

// Round 3
// 336.889 us; speedup vs baseline: 1.7785x; 1.2275x over previous
//
#include <hip/hip_runtime.h>
#include <math.h>

#define NHID 128
#define NFEAT 256
#define NCLASS 40

typedef __bf16 bf16x8 __attribute__((ext_vector_type(8)));
typedef __bf16 bf16x4 __attribute__((ext_vector_type(4)));
typedef float floatx4 __attribute__((ext_vector_type(4)));

// ===========================================================================
// CSR build via 2-level bucketed counting sort.
// Bucket = dst >> 8  (256 nodes/bucket, nbuck = ceil(N/256) = 196).
// Record = (dst&255)<<16 | src   (requires N <= 65536 -- true here, N=50000).
// ===========================================================================

// Pass A: bucket histogram. 4096 edges/block, LDS-aggregated.
__global__ __launch_bounds__(256) void bucket_hist(const int* __restrict__ edst,
                                                   int* __restrict__ bucket_counts,
                                                   int E, int nbuck) {
    __shared__ int lh[256];
    int tid = threadIdx.x;
    lh[tid] = 0;
    __syncthreads();
    int base = blockIdx.x * 4096;
#pragma unroll
    for (int k = 0; k < 16; ++k) {
        int e = base + k * 256 + tid;
        if (e < E) atomicAdd(&lh[edst[e] >> 8], 1);
    }
    __syncthreads();
    if (tid < nbuck && lh[tid]) atomicAdd(&bucket_counts[tid], lh[tid]);
}

// Scan bucket counts -> start (exclusive), cursor (= start), row_ptr[N] = E.
__global__ __launch_bounds__(256) void bucket_scan(const int* __restrict__ counts,
                                                   int* __restrict__ start,
                                                   int* __restrict__ cursor,
                                                   int* __restrict__ row_ptr,
                                                   int nbuck, int E, int N) {
    __shared__ int lds[256];
    int tid = threadIdx.x;
    int v = (tid < nbuck) ? counts[tid] : 0;
    lds[tid] = v;
    __syncthreads();
    for (int off = 1; off < 256; off <<= 1) {
        int t = (tid >= off) ? lds[tid - off] : 0;
        __syncthreads();
        lds[tid] += t;
        __syncthreads();
    }
    int excl = lds[tid] - v;
    if (tid < nbuck) { start[tid] = excl; cursor[tid] = excl; }
    if (tid == 0) { start[nbuck] = E; row_ptr[N] = E; }
}

// Pass B: scatter packed records into bucket segments. Per-block LDS
// aggregation -> one global atomic claim per (block,bucket) -> contiguous runs.
__global__ __launch_bounds__(256) void bucket_scatter(const int* __restrict__ esrc,
                                                      const int* __restrict__ edst,
                                                      int* __restrict__ cursor,
                                                      unsigned int* __restrict__ bdata,
                                                      int E, int nbuck) {
    __shared__ int lh[256];
    __shared__ int lbase[256];
    int tid = threadIdx.x;
    lh[tid] = 0;
    __syncthreads();
    int base = blockIdx.x * 4096;
    unsigned int recs[16];
    short bks[16];
    short lofs[16];
#pragma unroll
    for (int k = 0; k < 16; ++k) {
        int e = base + k * 256 + tid;
        bks[k] = -1;
        if (e < E) {
            int d = edst[e];
            int s = esrc[e];
            int b = d >> 8;
            recs[k] = ((unsigned int)(d & 255) << 16) | (unsigned int)s;
            bks[k] = (short)b;
            lofs[k] = (short)atomicAdd(&lh[b], 1);
        }
    }
    __syncthreads();
    if (tid < nbuck && lh[tid]) lbase[tid] = atomicAdd(&cursor[tid], lh[tid]);
    __syncthreads();
#pragma unroll
    for (int k = 0; k < 16; ++k) {
        if (bks[k] >= 0) bdata[lbase[bks[k]] + lofs[k]] = recs[k];
    }
}

// Pass C: one block per bucket. In-LDS counting sort of the bucket's records
// -> row_ptr (coalesced) + srcs (writes confined to one ~16KB region/block).
__global__ __launch_bounds__(256) void bucket_finalize(const unsigned int* __restrict__ bdata,
                                                       const int* __restrict__ start,
                                                       int* __restrict__ row_ptr,
                                                       int* __restrict__ srcs,
                                                       int N) {
    __shared__ int hist[256];
    __shared__ int cur[256];
    int b = blockIdx.x;
    int tid = threadIdx.x;
    int s0 = start[b];
    int cnt = start[b + 1] - s0;
    hist[tid] = 0;
    __syncthreads();
    for (int i = tid; i < cnt; i += 256) atomicAdd(&hist[bdata[s0 + i] >> 16], 1);
    __syncthreads();
    int v0 = hist[tid];
    __syncthreads();
    for (int off = 1; off < 256; off <<= 1) {
        int t = (tid >= off) ? hist[tid - off] : 0;
        __syncthreads();
        hist[tid] += t;
        __syncthreads();
    }
    int excl = hist[tid] - v0;
    cur[tid] = excl;
    int node = b * 256 + tid;
    if (node < N) row_ptr[node] = s0 + excl;
    __syncthreads();
    for (int i = tid; i < cnt; i += 256) {
        unsigned int r = bdata[s0 + i];
        int p = atomicAdd(&cur[r >> 16], 1);
        srcs[s0 + p] = (int)(r & 0xffffu);
    }
}

// ===========================================================================
// Weight prep: transpose + split fp32 W[K][128] -> Wt_hi/lo[128][K] bf16.
// ===========================================================================
template <int K>
__global__ __launch_bounds__(256) void transpose_split(const float* __restrict__ src,
                                                       __bf16* __restrict__ dhi,
                                                       __bf16* __restrict__ dlo, int total) {
    int i = blockIdx.x * 256 + threadIdx.x;
    if (i >= total) return;
    int per = 128 * K;
    int l = i / per;
    int r = i - l * per;
    int n = r / K;
    int k = r - n * K;
    float v = src[(size_t)l * per + (size_t)k * 128 + n];
    __bf16 hi = (__bf16)v;
    dhi[i] = hi;
    dlo[i] = (__bf16)(v - (float)hi);
}

// ===========================================================================
// Fused aggregate: sum = h[node] (hi+lo) + sum_{src in CSR} h_hi[src],
// written as bf16 hi/lo pair. One wave/node; row = 256B = 16 lanes x 16B,
// so each gather instruction covers 4 edges; unroll x2 -> 8 in flight.
// ===========================================================================
__global__ __launch_bounds__(256) void aggregate_fused(const __bf16* __restrict__ hhi,
                                                       const __bf16* __restrict__ hlo,
                                                       const int* __restrict__ row_ptr,
                                                       const int* __restrict__ srcs,
                                                       __bf16* __restrict__ ohi,
                                                       __bf16* __restrict__ olo, int N) {
    int tid = threadIdx.x;
    int node = blockIdx.x * 4 + (tid >> 6);
    if (node >= N) return;
    int lane = tid & 63;
    int g = lane >> 4;   // edge slot 0..3
    int c = lane & 15;   // 16B chunk (8 bf16 features)
    int beg = row_ptr[node];
    int end = row_ptr[node + 1];
    const bf16x8* hv = (const bf16x8*)hhi;

    float a[8], b2[8];
#pragma unroll
    for (int j = 0; j < 8; ++j) { a[j] = 0.f; b2[j] = 0.f; }

    int i = beg;
    for (; i + 8 <= end; i += 8) {
        int s0 = srcs[i + g];
        int s1 = srcs[i + 4 + g];
        bf16x8 v0 = hv[(size_t)s0 * 16 + c];
        bf16x8 v1 = hv[(size_t)s1 * 16 + c];
#pragma unroll
        for (int j = 0; j < 8; ++j) { a[j] += (float)v0[j]; b2[j] += (float)v1[j]; }
    }
    for (; i < end; i += 4) {
        if (i + g < end) {
            int s = srcs[i + g];
            bf16x8 v = hv[(size_t)s * 16 + c];
#pragma unroll
            for (int j = 0; j < 8; ++j) a[j] += (float)v[j];
        }
    }
#pragma unroll
    for (int j = 0; j < 8; ++j) a[j] += b2[j];
#pragma unroll
    for (int j = 0; j < 8; ++j) a[j] += __shfl_xor(a[j], 16);
#pragma unroll
    for (int j = 0; j < 8; ++j) a[j] += __shfl_xor(a[j], 32);

    if (g == 0) {
        bf16x8 sh = ((const bf16x8*)hhi)[(size_t)node * 16 + c];
        bf16x8 sl = ((const bf16x8*)hlo)[(size_t)node * 16 + c];
        bf16x8 whi, wlo;
#pragma unroll
        for (int j = 0; j < 8; ++j) {
            float v = a[j] + (float)sh[j] + (float)sl[j];
            __bf16 h = (__bf16)v;
            whi[j] = h;
            wlo[j] = (__bf16)(v - (float)h);
        }
        ((bf16x8*)ohi)[(size_t)node * 16 + c] = whi;
        ((bf16x8*)olo)[(size_t)node * 16 + c] = wlo;
    }
}

// ===========================================================================
// MFMA GEMM: out = relu(A @ W + b), N=128, split-precision bf16.
// MODE 0: A = fp32 Af[M][K] (input layer, K=256) -- split in staging.
// MODE 1: A = bf16 hi/lo pair (fused aggregate output, K=128) -- pure copy.
// Tile 64x128, BK=64, XOR-swizzled LDS, 3 MFMAs per frag (hi*hi+lo*hi+hi*lo).
// ===========================================================================
template <int MODE>
__global__ __launch_bounds__(256) void gemm_mfma(
    const float* __restrict__ Af, const __bf16* __restrict__ Ahi,
    const __bf16* __restrict__ Alo,
    const __bf16* __restrict__ Wthi, const __bf16* __restrict__ Wtlo,
    const float* __restrict__ bias, __bf16* __restrict__ Ohi,
    __bf16* __restrict__ Olo, int M, int K) {
    __shared__ __align__(16) char smem[49152];
    __bf16* sAhi = (__bf16*)smem;                // 64x64 = 8KB
    __bf16* sAlo = (__bf16*)(smem + 8192);       // 8KB
    __bf16* sWhi = (__bf16*)(smem + 16384);      // 128x64 = 16KB
    __bf16* sWlo = (__bf16*)(smem + 32768);      // 16KB

    int tid = threadIdx.x;
    int row0 = blockIdx.x * 64;
    int wave = tid >> 6;
    int l = tid & 63;
    int m16 = l & 15;
    int q = l >> 4;
    int axor = m16 & 7;
    int arow = wave * 16 + m16;

    floatx4 acc[8];
#pragma unroll
    for (int t = 0; t < 8; ++t) acc[t] = (floatx4){0.f, 0.f, 0.f, 0.f};

    for (int k0 = 0; k0 < K; k0 += 64) {
        // ---- stage A tile (64 x 64) ----
#pragma unroll
        for (int it = 0; it < 2; ++it) {
            int lin = it * 2048 + tid * 8;
            int row = lin >> 6, k = lin & 63;
            int g = min(row0 + row, M - 1);
            int off = row * 64 + (((k >> 3) ^ (row & 7)) << 3);
            if (MODE == 0) {
                float4 v0 = *(const float4*)&Af[(size_t)g * K + k0 + k];
                float4 v1 = *(const float4*)&Af[(size_t)g * K + k0 + k + 4];
                float s[8] = {v0.x, v0.y, v0.z, v0.w, v1.x, v1.y, v1.z, v1.w};
                bf16x8 shi, slo;
#pragma unroll
                for (int j = 0; j < 8; ++j) {
                    __bf16 h = (__bf16)s[j];
                    shi[j] = h;
                    slo[j] = (__bf16)(s[j] - (float)h);
                }
                *(bf16x8*)(sAhi + off) = shi;
                *(bf16x8*)(sAlo + off) = slo;
            } else {
                *(bf16x8*)(sAhi + off) = *(const bf16x8*)&Ahi[(size_t)g * 128 + k0 + k];
                *(bf16x8*)(sAlo + off) = *(const bf16x8*)&Alo[(size_t)g * 128 + k0 + k];
            }
        }
        // ---- stage W tile (128 x 64) ----
#pragma unroll
        for (int it = 0; it < 4; ++it) {
            int lin = it * 2048 + tid * 8;
            int n = lin >> 6, kk = lin & 63;
            int off = n * 64 + (((kk >> 3) ^ (n & 7)) << 3);
            *(bf16x8*)(sWhi + off) = *(const bf16x8*)&Wthi[(size_t)n * K + k0 + kk];
            *(bf16x8*)(sWlo + off) = *(const bf16x8*)&Wtlo[(size_t)n * K + k0 + kk];
        }
        __syncthreads();

#pragma unroll
        for (int s = 0; s < 2; ++s) {
            int sw = (((s * 4 + q) ^ axor) << 3);
            bf16x8 ahi = *(bf16x8*)(sAhi + arow * 64 + sw);
            bf16x8 alo = *(bf16x8*)(sAlo + arow * 64 + sw);
#pragma unroll
            for (int t = 0; t < 8; ++t) {
                int n = t * 16 + m16;
                bf16x8 bhi = *(bf16x8*)(sWhi + n * 64 + sw);
                bf16x8 blo = *(bf16x8*)(sWlo + n * 64 + sw);
                acc[t] = __builtin_amdgcn_mfma_f32_16x16x32_bf16(ahi, bhi, acc[t], 0, 0, 0);
                acc[t] = __builtin_amdgcn_mfma_f32_16x16x32_bf16(alo, bhi, acc[t], 0, 0, 0);
                acc[t] = __builtin_amdgcn_mfma_f32_16x16x32_bf16(ahi, blo, acc[t], 0, 0, 0);
            }
        }
        __syncthreads();
    }

    // ---- epilogue: bias + relu -> fp32 LDS -> coalesced bf16 hi/lo ----
    float* eps = (float*)(smem + 16384);  // 64*128*4 = 32KB
#pragma unroll
    for (int t = 0; t < 8; ++t) {
        int col = t * 16 + m16;
        float bb = bias[col];
#pragma unroll
        for (int i = 0; i < 4; ++i) {
            int row = wave * 16 + q * 4 + i;
            eps[row * 128 + col] = fmaxf(acc[t][i] + bb, 0.f);
        }
    }
    __syncthreads();
#pragma unroll
    for (int it = 0; it < 8; ++it) {
        int lin = it * 1024 + tid * 4;
        int row = lin >> 7, col = lin & 127;
        int g = row0 + row;
        if (g < M) {
            float4 v = *(float4*)(eps + lin);
            bf16x4 hi, lo;
            float vv[4] = {v.x, v.y, v.z, v.w};
#pragma unroll
            for (int j = 0; j < 4; ++j) {
                __bf16 h = (__bf16)vv[j];
                hi[j] = h;
                lo[j] = (__bf16)(vv[j] - (float)h);
            }
            *(bf16x4*)&Ohi[(size_t)g * 128 + col] = hi;
            *(bf16x4*)&Olo[(size_t)g * 128 + col] = lo;
        }
    }
}

// ===========================================================================
// Output: logits = h @ W_out + b_out (K=128, C=40), then row log_softmax.
// ===========================================================================
__global__ __launch_bounds__(256) void out_logsoftmax(const __bf16* __restrict__ hhi,
                                                      const __bf16* __restrict__ hlo,
                                                      const float* __restrict__ Wout,
                                                      const float* __restrict__ bout,
                                                      float* __restrict__ out, int M) {
    __shared__ float sW[128 * NCLASS];
    __shared__ float sb[NCLASS];
    __shared__ float sH[32 * 132];
    int tid = threadIdx.x;
    for (int i = tid; i < 128 * NCLASS; i += 256) sW[i] = Wout[i];
    if (tid < NCLASS) sb[tid] = bout[tid];
    int row0 = blockIdx.x * 32;
#pragma unroll
    for (int it = 0; it < 4; ++it) {
        int i = tid * 4 + it * 1024;
        int r = i >> 7, k = i & 127;
        int rr = min(row0 + r, M - 1);
        uint2 uh = *(const uint2*)&hhi[(size_t)rr * 128 + k];
        uint2 ul = *(const uint2*)&hlo[(size_t)rr * 128 + k];
        sH[r * 132 + k + 0] = __uint_as_float(uh.x << 16) + __uint_as_float(ul.x << 16);
        sH[r * 132 + k + 1] = __uint_as_float(uh.x & 0xffff0000u) + __uint_as_float(ul.x & 0xffff0000u);
        sH[r * 132 + k + 2] = __uint_as_float(uh.y << 16) + __uint_as_float(ul.y << 16);
        sH[r * 132 + k + 3] = __uint_as_float(uh.y & 0xffff0000u) + __uint_as_float(ul.y & 0xffff0000u);
    }
    __syncthreads();

    int r = tid >> 3;
    int cg = tid & 7;
    float z[5];
#pragma unroll
    for (int j = 0; j < 5; ++j) z[j] = sb[cg * 5 + j];
    for (int k = 0; k < 128; ++k) {
        float a = sH[r * 132 + k];
#pragma unroll
        for (int j = 0; j < 5; ++j) z[j] += a * sW[k * NCLASS + cg * 5 + j];
    }
    float m = z[0];
#pragma unroll
    for (int j = 1; j < 5; ++j) m = fmaxf(m, z[j]);
    for (int off = 1; off < 8; off <<= 1) m = fmaxf(m, __shfl_xor(m, off));
    float s = 0.f;
#pragma unroll
    for (int j = 0; j < 5; ++j) s += expf(z[j] - m);
    for (int off = 1; off < 8; off <<= 1) s += __shfl_xor(s, off);
    float lse = m + logf(s);
    int row = row0 + r;
    if (row < M) {
#pragma unroll
        for (int j = 0; j < 5; ++j) out[(size_t)row * NCLASS + cg * 5 + j] = z[j] - lse;
    }
}

// ===========================================================================
extern "C" void kernel_launch(void* const* d_in, const int* in_sizes, int n_in,
                              void* d_out, int out_size, void* d_ws, size_t ws_size,
                              hipStream_t stream) {
    const float* x      = (const float*)d_in[0];
    const int*   esrc   = (const int*)d_in[1];
    const int*   edst   = (const int*)d_in[2];
    const float* W_in   = (const float*)d_in[3];
    const float* b_in   = (const float*)d_in[4];
    const float* W_mlps = (const float*)d_in[5];
    const float* b_mlps = (const float*)d_in[6];
    const float* W_out  = (const float*)d_in[7];
    const float* b_out  = (const float*)d_in[8];
    float* out = (float*)d_out;

    int N = in_sizes[0] / NFEAT;  // 50000
    int E = in_sizes[1];          // 800000
    int nbuck = (N + 255) >> 8;   // 196

    // workspace carve (~80.6 MB)
    char* ws = (char*)d_ws;
    size_t hb = (((size_t)N * NHID * sizeof(__bf16)) + 255) & ~(size_t)255;  // 12.8MB
    __bf16* h_hi_a = (__bf16*)ws;
    __bf16* h_lo_a = (__bf16*)(ws + hb);
    __bf16* h_hi_b = (__bf16*)(ws + 2 * hb);
    __bf16* h_lo_b = (__bf16*)(ws + 3 * hb);
    __bf16* sum_hi = (__bf16*)(ws + 4 * hb);
    __bf16* sum_lo = (__bf16*)(ws + 5 * hb);
    // bdata aliases sum_hi's slot: used only during CSR build (before any aggregate)
    unsigned int* bdata = (unsigned int*)(ws + 4 * hb);
    char* ip = ws + 6 * hb;
    int* row_ptr = (int*)ip;  ip += (((size_t)(N + 1) * 4) + 255) & ~(size_t)255;
    int* srcs    = (int*)ip;  ip += (((size_t)E * 4) + 255) & ~(size_t)255;
    int* bucket_counts = (int*)ip;  ip += 1024;
    int* bucket_start  = (int*)ip;  ip += 1024;
    int* bucket_cursor = (int*)ip;  ip += 1024;
    __bf16* Wt_in_hi   = (__bf16*)ip;  ip += 128 * NFEAT * 2;
    __bf16* Wt_in_lo   = (__bf16*)ip;  ip += 128 * NFEAT * 2;
    __bf16* Wt_mlps_hi = (__bf16*)ip;  ip += 3 * 128 * NHID * 2;
    __bf16* Wt_mlps_lo = (__bf16*)ip;  ip += 3 * 128 * NHID * 2;

    int eb4 = (E + 4095) / 4096;

    // ---- CSR build (bucketed counting sort) ----
    hipMemsetAsync(bucket_counts, 0, 1024, stream);
    bucket_hist<<<eb4, 256, 0, stream>>>(edst, bucket_counts, E, nbuck);
    bucket_scan<<<1, 256, 0, stream>>>(bucket_counts, bucket_start, bucket_cursor,
                                       row_ptr, nbuck, E, N);
    bucket_scatter<<<eb4, 256, 0, stream>>>(esrc, edst, bucket_cursor, bdata, E, nbuck);
    bucket_finalize<<<nbuck, 256, 0, stream>>>(bdata, bucket_start, row_ptr, srcs, N);

    // ---- weight prep ----
    transpose_split<NFEAT><<<(128 * NFEAT + 255) / 256, 256, 0, stream>>>(
        W_in, Wt_in_hi, Wt_in_lo, 128 * NFEAT);
    transpose_split<NHID><<<(3 * 128 * NHID + 255) / 256, 256, 0, stream>>>(
        W_mlps, Wt_mlps_hi, Wt_mlps_lo, 3 * 128 * NHID);

    int gb = (N + 63) / 64;
    // ---- input layer ----
    gemm_mfma<0><<<gb, 256, 0, stream>>>(x, (const __bf16*)nullptr, (const __bf16*)nullptr,
                                         Wt_in_hi, Wt_in_lo, b_in, h_hi_a, h_lo_a, N, NFEAT);

    // ---- 3 GIN layers ----
    __bf16* cur_hi = h_hi_a; __bf16* cur_lo = h_lo_a;
    __bf16* nxt_hi = h_hi_b; __bf16* nxt_lo = h_lo_b;
    for (int i = 0; i < 3; ++i) {
        aggregate_fused<<<(N + 3) / 4, 256, 0, stream>>>(cur_hi, cur_lo, row_ptr, srcs,
                                                         sum_hi, sum_lo, N);
        gemm_mfma<1><<<gb, 256, 0, stream>>>(
            (const float*)nullptr, sum_hi, sum_lo,
            Wt_mlps_hi + (size_t)i * 128 * NHID, Wt_mlps_lo + (size_t)i * 128 * NHID,
            b_mlps + (size_t)i * NHID, nxt_hi, nxt_lo, N, NHID);
        __bf16* t;
        t = cur_hi; cur_hi = nxt_hi; nxt_hi = t;
        t = cur_lo; cur_lo = nxt_lo; nxt_lo = t;
    }

    // ---- output layer + log_softmax ----
    out_logsoftmax<<<(N + 31) / 32, 256, 0, stream>>>(cur_hi, cur_lo, W_out, b_out, out, N);
}